// Round 1
// baseline (194.043 us; speedup 1.0000x reference)
//
#include <hip/hip_runtime.h>

#define VOCAB 40
#define SEQ 128
#define THREADS 256
#define HSTRIDE 11  // 10 histogram words + 1 pad word -> gcd(11,32)=1, conflict-free

__global__ __launch_bounds__(THREADS) void char_dist_kernel(
    const int* __restrict__ x, float* __restrict__ out, int batch) {
  __shared__ unsigned int hist[THREADS * HSTRIDE];
  const int tid = threadIdx.x;
  const int row = blockIdx.x * THREADS + tid;
  if (row >= batch) return;

  unsigned int* h = &hist[tid * HSTRIDE];
#pragma unroll
  for (int w = 0; w < 10; ++w) h[w] = 0u;
  // No barrier needed: each thread touches only its own LDS region.

  const int4* rowp = reinterpret_cast<const int4*>(x + (long)row * SEQ);
#pragma unroll 4
  for (int j = 0; j < SEQ / 4; ++j) {
    int4 t = rowp[j];
    int v;
    v = t.x; h[v >> 2] += 1u << ((v & 3) << 3);
    v = t.y; h[v >> 2] += 1u << ((v & 3) << 3);
    v = t.z; h[v >> 2] += 1u << ((v & 3) << 3);
    v = t.w; h[v >> 2] += 1u << ((v & 3) << 3);
  }

  int total = 0, uniq = 0, maxc = 0, minc = 256;
  int letters = 0, digits = 0, special = 0;
#pragma unroll
  for (int w = 0; w < 10; ++w) {
    unsigned int word = h[w];
#pragma unroll
    for (int b = 0; b < 4; ++b) {
      const int v = w * 4 + b;
      if (v == 0) continue;  // bin 0 is padding: reference scatters 0.0 there
      if (v >= VOCAB) continue;
      int c = (int)((word >> (b * 8)) & 0xFFu);
      total += c;
      uniq += (c > 0) ? 1 : 0;
      maxc = max(maxc, c);
      if (c > 0) minc = min(minc, c);
      if (v <= 26) letters += c;
      else if (v <= 36) digits += c;
      else special += c;
    }
  }

  float f0, f1, f2, f3, f4, f5;
  if (total > 0) {
    float inv = 1.0f / (float)total;
    f0 = (float)uniq * (1.0f / (float)VOCAB);
    f1 = (float)maxc * inv;
    f2 = (float)minc * inv;
    f3 = (float)letters * inv;
    f4 = (float)digits * inv;
    f5 = (float)special * inv;
  } else {
    f0 = f1 = f2 = f3 = f4 = f5 = 0.0f;
  }

  float2* o = reinterpret_cast<float2*>(out + (long)row * 6);
  o[0] = make_float2(f0, f1);
  o[1] = make_float2(f2, f3);
  o[2] = make_float2(f4, f5);
}

extern "C" void kernel_launch(void* const* d_in, const int* in_sizes, int n_in,
                              void* d_out, int out_size, void* d_ws, size_t ws_size,
                              hipStream_t stream) {
  const int* x = (const int*)d_in[0];
  float* out = (float*)d_out;
  const int batch = in_sizes[0] / SEQ;
  const int blocks = (batch + THREADS - 1) / THREADS;
  char_dist_kernel<<<blocks, THREADS, 0, stream>>>(x, out, batch);
}